// Round 5
// baseline (338.245 us; speedup 1.0000x reference)
//
#include <hip/hip_runtime.h>
#include <hip/hip_bf16.h>

typedef __attribute__((ext_vector_type(8))) short short8;      // 8 x bf16
typedef __attribute__((ext_vector_type(16))) float f32x16;     // 32x32 MFMA C/D
typedef __attribute__((ext_vector_type(4))) unsigned int uint4v;

#define NB 2
#define NS 2048
#define NH 16
#define ND 128
#define ROWS (NH * ND)       // 2048 floats between consecutive seq positions
#define KVBLK 64
#define QBLK 128             // 4 waves x 32 q-rows
#define NTILE (NS / KVBLK)   // 32
#define NQB (NS / QBLK)      // 16
#define NSPLIT 2
#define TILES_PER_SPLIT (NTILE / NSPLIT)  // 16
#define ELEMS ((size_t)NB * NH * NS * ND)  // 8.39M
#define LCNT ((size_t)NB * NS * NH)        // 65536

__device__ __forceinline__ unsigned short f2bf(float f) {
  union { __hip_bfloat16 b; unsigned short u; } c;
  c.b = __float2bfloat16(f);  // RNE
  return c.u;
}

__device__ __forceinline__ short8 pack8(float4 a, float4 b, float s) {
  short8 r;
  r[0] = (short)f2bf(a.x * s); r[1] = (short)f2bf(a.y * s);
  r[2] = (short)f2bf(a.z * s); r[3] = (short)f2bf(a.w * s);
  r[4] = (short)f2bf(b.x * s); r[5] = (short)f2bf(b.y * s);
  r[6] = (short)f2bf(b.z * s); r[7] = (short)f2bf(b.w * s);
  return r;
}

__device__ __forceinline__ void dma16(const void* g, void* l) {
  __builtin_amdgcn_global_load_lds(
      (const __attribute__((address_space(1))) unsigned int*)g,
      (__attribute__((address_space(3))) unsigned int*)l, 16, 0, 0);
}

__device__ __forceinline__ void pl32swap(unsigned int& a, unsigned int& b) {
  asm("v_permlane32_swap_b32 %0, %1" : "+v"(a), "+v"(b));
}

// ---------------- prepass: K -> bf16 [b,h,s,d]; V -> bf16 transposed [b,h,d,s] ----
__global__ __launch_bounds__(256) void prepass_kv(
    const float* __restrict__ Kg, const float* __restrict__ Vg,
    unsigned short* __restrict__ Kb, unsigned short* __restrict__ Vt) {
  const int blk = blockIdx.x;          // bh*NTILE + t
  const int t = blk & (NTILE - 1);
  const int bh = blk >> 5;
  const int h = bh & (NH - 1);
  const int b = bh >> 4;
  const int tid = threadIdx.x;

  const size_t ibase = (size_t)b * NS * ROWS + (size_t)h * ND + (size_t)t * KVBLK * ROWS;
  const float* Kp = Kg + ibase;
  const float* Vp = Vg + ibase;
  unsigned short* Kbp = Kb + ((size_t)bh * NS + t * KVBLK) * ND;   // [s][d]
  unsigned short* Vtp = Vt + (size_t)bh * ND * NS + t * KVBLK;     // [d][s]

#pragma unroll
  for (int j = 0; j < 4; ++j) {
    const int r = j * 16 + (tid >> 4);
    const int c0 = (tid & 15) * 8;
    float4 a = *reinterpret_cast<const float4*>(Kp + (size_t)r * ROWS + c0);
    float4 c = *reinterpret_cast<const float4*>(Kp + (size_t)r * ROWS + c0 + 4);
    *reinterpret_cast<short8*>(Kbp + r * ND + c0) = pack8(a, c, 1.0f);
  }

  __shared__ float vt[64][129];
#pragma unroll
  for (int j = 0; j < 4; ++j) {
    const int r = j * 16 + (tid >> 4);
    const int c0 = (tid & 15) * 8;
    float4 a = *reinterpret_cast<const float4*>(Vp + (size_t)r * ROWS + c0);
    float4 c = *reinterpret_cast<const float4*>(Vp + (size_t)r * ROWS + c0 + 4);
    vt[r][c0 + 0] = a.x; vt[r][c0 + 1] = a.y; vt[r][c0 + 2] = a.z; vt[r][c0 + 3] = a.w;
    vt[r][c0 + 4] = c.x; vt[r][c0 + 5] = c.y; vt[r][c0 + 6] = c.z; vt[r][c0 + 7] = c.w;
  }
  __syncthreads();
#pragma unroll
  for (int dj = 0; dj < 4; ++dj) {
    const int d = dj * 32 + (tid >> 3);
    const int s0 = (tid & 7) * 8;
    short8 o8;
#pragma unroll
    for (int k = 0; k < 8; ++k) o8[k] = (short)f2bf(vt[s0 + k][d]);
    *reinterpret_cast<short8*>(Vtp + (size_t)d * NS + s0) = o8;
  }
}

// ---------------- split-KV main: 1024 blocks (4/CU, 16 waves/CU), 16 tiles each ----
// S^T = mfma(A=K, B=Q); O^T = mfma(A=V^T, B=P^T), P^T in-register (permlane32_swap).
// No-max softmax -> splits combine by pure addition: O = (O0+O1)/(l0+l1).
__global__ __launch_bounds__(256, 4) void fattn_split(
    const float* __restrict__ Qg, const unsigned short* __restrict__ Kb,
    const unsigned short* __restrict__ Vt, float* __restrict__ Obase,
    float* __restrict__ Lbase) {
  __shared__ __align__(16) char lds[32768];   // single buffer: 4 blocks/CU fit
  char* ksb = lds;
  char* vtb = lds + 16384;
  const int tid = threadIdx.x;
  const int l = tid & 63;
  const int w = tid >> 6;
  const int l31 = l & 31;
  const int hi2 = l >> 5;

  // Bijective XCD swizzle (nwg=1024, %8==0); bh-major work order.
  const int orig = blockIdx.x;
  const int wg = (orig & 7) * 128 + (orig >> 3);
  const int split = wg & 1;
  const int qblk = (wg >> 1) & (NQB - 1);
  const int bh = wg >> 5;
  const int h = bh & (NH - 1);
  const int b = bh >> 4;

  float* Opart = Obase + (size_t)split * ELEMS;
  float* Lpart = Lbase + (size_t)split * LCNT;

  const float* Qp = Qg + (size_t)b * NS * ROWS + (size_t)h * ND;
  const char* Kbh = (const char*)(Kb + (size_t)bh * NS * ND);   // bf16 [s][d], 256B/row
  const char* Vth = (const char*)(Vt + (size_t)bh * ND * NS);   // bf16 [d][s], 4096B/row

  const float scale = 0.08838834764831845f * 1.4426950408889634f;  // 1/sqrt(D)*log2e

  const int qrow = qblk * QBLK + w * 32 + l31;
  short8 qf[8];
  {
    const float* qr = Qp + (size_t)qrow * ROWS + hi2 * 8;
#pragma unroll
    for (int ks = 0; ks < 8; ++ks) {
      float4 a = *reinterpret_cast<const float4*>(qr + ks * 16);
      float4 c = *reinterpret_cast<const float4*>(qr + ks * 16 + 4);
      qf[ks] = pack8(a, c, scale);
    }
  }

  f32x16 o[4];
#pragma unroll
  for (int dt = 0; dt < 4; ++dt) o[dt] = 0.f;
  float l_acc = 0.f;

  const int t0 = split * TILES_PER_SPLIT;
#pragma unroll 1
  for (int tt = 0; tt < TILES_PER_SPLIT; ++tt) {
    const int t = t0 + tt;
    __syncthreads();  // all waves done reading previous tile

    // K tile DMA: LDS linear, source pre-swizzled (involution (row&7)<<4)
    {
      const char* Kt = Kbh + (size_t)t * KVBLK * 256;
#pragma unroll
      for (int i = 0; i < 4; ++i) {
        const int instr = w * 4 + i;              // 1KB per instr = 4 K-rows
        const int row = instr * 4 + (l >> 4);
        const int x = (l & 15) << 4;
        dma16(Kt + row * 256 + (x ^ ((row & 7) << 4)), ksb + instr * 1024);
      }
    }
    // V^T tile DMA
    {
      const char* Vtt = Vth + (size_t)t * KVBLK * 2;
#pragma unroll
      for (int j = 0; j < 4; ++j) {
        const int instr = w * 4 + j;              // 1KB per instr = 8 V d-rows
        const int d = instr * 8 + (l >> 3);
        const int x = (l & 7) << 4;
        dma16(Vtt + (size_t)d * (NS * 2) + (x ^ ((d & 7) << 4)), vtb + instr * 1024);
      }
    }
    asm volatile("s_waitcnt vmcnt(0)" ::: "memory");
    __syncthreads();

    // S^T = K Q^T : 2 m-tiles x 8 k-steps over d
    f32x16 st[2];
    __builtin_amdgcn_s_setprio(1);
#pragma unroll
    for (int mt = 0; mt < 2; ++mt) {
      f32x16 acc = 0.f;
      const int row = mt * 32 + l31;
#pragma unroll
      for (int ks = 0; ks < 8; ++ks) {
        short8 kf = *reinterpret_cast<const short8*>(
            ksb + row * 256 + ((ks * 32 + hi2 * 16) ^ ((row & 7) << 4)));
        acc = __builtin_amdgcn_mfma_f32_32x32x16_bf16(kf, qf[ks], acc, 0, 0, 0);
      }
      st[mt] = acc;
    }
    __builtin_amdgcn_s_setprio(0);

    // p = exp2(st) (log2e pre-folded); lane-local l sum, cross-half swap deferred
    f32x16 p0, p1;
#pragma unroll
    for (int r = 0; r < 16; ++r) p0[r] = exp2f(st[0][r]);
#pragma unroll
    for (int r = 0; r < 16; ++r) p1[r] = exp2f(st[1][r]);
    {
      float s = 0.f;
#pragma unroll
      for (int r = 0; r < 16; ++r) s += p0[r] + p1[r];
      l_acc += s;
    }

    // P^T B-frags in-register: pack pairs to bf16, permlane32_swap halves
    short8 pf[4];
#pragma unroll
    for (int mt = 0; mt < 2; ++mt) {
      const f32x16& pp = mt ? p1 : p0;
      unsigned int X[8];
#pragma unroll
      for (int j = 0; j < 8; ++j)
        X[j] = (unsigned int)f2bf(pp[2 * j]) | ((unsigned int)f2bf(pp[2 * j + 1]) << 16);
      pl32swap(X[0], X[2]); pl32swap(X[1], X[3]);
      pl32swap(X[4], X[6]); pl32swap(X[5], X[7]);
      uint4v lo_ = {X[0], X[1], X[2], X[3]};
      uint4v hi_ = {X[4], X[5], X[6], X[7]};
      pf[mt * 2 + 0] = __builtin_bit_cast(short8, lo_);
      pf[mt * 2 + 1] = __builtin_bit_cast(short8, hi_);
    }

    // O^T += V^T P^T : 4 d-tiles x 4 k-steps
    __builtin_amdgcn_s_setprio(1);
#pragma unroll
    for (int dt = 0; dt < 4; ++dt) {
      const int d = dt * 32 + l31;
#pragma unroll
      for (int ks = 0; ks < 4; ++ks) {
        short8 vf = *reinterpret_cast<const short8*>(
            vtb + d * 128 + ((ks * 32 + hi2 * 16) ^ ((d & 7) << 4)));
        o[dt] = __builtin_amdgcn_mfma_f32_32x32x16_bf16(vf, pf[ks], o[dt], 0, 0, 0);
      }
    }
    __builtin_amdgcn_s_setprio(0);
  }

  // epilogue: UNNORMALIZED partial O + l, layout [b,s,h,d] (matches d_out)
  const float lt = l_acc + __shfl_xor(l_acc, 32);
  float* orow = Opart + ((size_t)(b * NS + qrow) * NH + h) * ND;
#pragma unroll
  for (int dt = 0; dt < 4; ++dt) {
#pragma unroll
    for (int g = 0; g < 4; ++g) {
      float4 v;
      v.x = o[dt][g * 4 + 0];
      v.y = o[dt][g * 4 + 1];
      v.z = o[dt][g * 4 + 2];
      v.w = o[dt][g * 4 + 3];
      *reinterpret_cast<float4*>(orow + dt * 32 + g * 8 + hi2 * 4) = v;
    }
  }
  if (hi2 == 0) Lpart[(size_t)(b * NS + qrow) * NH + h] = lt;
}

// ---------------- combine: out = (O0+O1)/(l0+l1), elementwise ----
__global__ __launch_bounds__(256) void combine_splits(
    const float4* __restrict__ O0, const float4* __restrict__ O1,
    const float* __restrict__ L0, const float* __restrict__ L1,
    float4* __restrict__ out, int nf4) {
  int i = blockIdx.x * 256 + threadIdx.x;
  const int stride = gridDim.x * 256;
  for (; i < nf4; i += stride) {
    const int r = i >> 5;  // 32 float4 per 128-d row; r = flat (b,s,h)
    float4 a = O0[i];
    float4 c = O1[i];
    const float inv = 1.0f / (L0[r] + L1[r]);
    float4 v;
    v.x = (a.x + c.x) * inv;
    v.y = (a.y + c.y) * inv;
    v.z = (a.z + c.z) * inv;
    v.w = (a.w + c.w) * inv;
    out[i] = v;
  }
}

// ---------------- fallback (R4 dbuf kernel), used only if ws too small ----------
__global__ __launch_bounds__(256, 2) void fattn_fwd(
    const float* __restrict__ Qg, const unsigned short* __restrict__ Kb,
    const unsigned short* __restrict__ Vt, float* __restrict__ Og) {
  __shared__ __align__(16) char lds[65536];
  const int tid = threadIdx.x;
  const int l = tid & 63;
  const int w = tid >> 6;
  const int l31 = l & 31;
  const int hi2 = l >> 5;
  const int orig = blockIdx.x;
  const int wg = (orig & 7) * 64 + (orig >> 3);
  const int qblk = wg & (NQB - 1);
  const int bh = wg >> 4;
  const int h = bh & (NH - 1);
  const int b = bh >> 4;
  const float* Qp = Qg + (size_t)b * NS * ROWS + (size_t)h * ND;
  float* Op = Og + (size_t)b * NS * ROWS + (size_t)h * ND;
  const char* Kbh = (const char*)(Kb + (size_t)bh * NS * ND);
  const char* Vth = (const char*)(Vt + (size_t)bh * ND * NS);
  const float scale = 0.08838834764831845f * 1.4426950408889634f;
  const int qrow = qblk * QBLK + w * 32 + l31;
  short8 qf[8];
  {
    const float* qr = Qp + (size_t)qrow * ROWS + hi2 * 8;
#pragma unroll
    for (int ks = 0; ks < 8; ++ks) {
      float4 a = *reinterpret_cast<const float4*>(qr + ks * 16);
      float4 c = *reinterpret_cast<const float4*>(qr + ks * 16 + 4);
      qf[ks] = pack8(a, c, scale);
    }
  }
  auto stage = [&](int t, char* kd, char* vd) {
    const char* Kt = Kbh + (size_t)t * KVBLK * 256;
#pragma unroll
    for (int i = 0; i < 4; ++i) {
      const int instr = w * 4 + i;
      const int row = instr * 4 + (l >> 4);
      const int x = (l & 15) << 4;
      dma16(Kt + row * 256 + (x ^ ((row & 7) << 4)), kd + instr * 1024);
    }
    const char* Vtt = Vth + (size_t)t * KVBLK * 2;
#pragma unroll
    for (int j = 0; j < 4; ++j) {
      const int instr = w * 4 + j;
      const int d = instr * 8 + (l >> 3);
      const int x = (l & 7) << 4;
      dma16(Vtt + (size_t)d * (NS * 2) + (x ^ ((d & 7) << 4)), vd + instr * 1024);
    }
  };
  f32x16 o[4];
#pragma unroll
  for (int dt = 0; dt < 4; ++dt) o[dt] = 0.f;
  float l_acc = 0.f;
  stage(0, lds, lds + 16384);
  asm volatile("s_waitcnt vmcnt(0)" ::: "memory");
  __syncthreads();
#pragma unroll 1
  for (int t = 0; t < NTILE; ++t) {
    char* ksb = lds + (t & 1) * 32768;
    char* vtb = ksb + 16384;
    if (t + 1 < NTILE) {
      char* kn = lds + ((t + 1) & 1) * 32768;
      stage(t + 1, kn, kn + 16384);
    }
    f32x16 st[2];
#pragma unroll
    for (int mt = 0; mt < 2; ++mt) {
      f32x16 acc = 0.f;
      const int row = mt * 32 + l31;
#pragma unroll
      for (int ks = 0; ks < 8; ++ks) {
        short8 kf = *reinterpret_cast<const short8*>(
            ksb + row * 256 + ((ks * 32 + hi2 * 16) ^ ((row & 7) << 4)));
        acc = __builtin_amdgcn_mfma_f32_32x32x16_bf16(kf, qf[ks], acc, 0, 0, 0);
      }
      st[mt] = acc;
    }
    f32x16 p0, p1;
#pragma unroll
    for (int r = 0; r < 16; ++r) p0[r] = exp2f(st[0][r]);
#pragma unroll
    for (int r = 0; r < 16; ++r) p1[r] = exp2f(st[1][r]);
    {
      float s = 0.f;
#pragma unroll
      for (int r = 0; r < 16; ++r) s += p0[r] + p1[r];
      l_acc += s;
    }
    short8 pf[4];
#pragma unroll
    for (int mt = 0; mt < 2; ++mt) {
      const f32x16& pp = mt ? p1 : p0;
      unsigned int X[8];
#pragma unroll
      for (int j = 0; j < 8; ++j)
        X[j] = (unsigned int)f2bf(pp[2 * j]) | ((unsigned int)f2bf(pp[2 * j + 1]) << 16);
      pl32swap(X[0], X[2]); pl32swap(X[1], X[3]);
      pl32swap(X[4], X[6]); pl32swap(X[5], X[7]);
      uint4v lo_ = {X[0], X[1], X[2], X[3]};
      uint4v hi_ = {X[4], X[5], X[6], X[7]};
      pf[mt * 2 + 0] = __builtin_bit_cast(short8, lo_);
      pf[mt * 2 + 1] = __builtin_bit_cast(short8, hi_);
    }
#pragma unroll
    for (int dt = 0; dt < 4; ++dt) {
      const int d = dt * 32 + l31;
#pragma unroll
      for (int ks = 0; ks < 4; ++ks) {
        short8 vf = *reinterpret_cast<const short8*>(
            vtb + d * 128 + ((ks * 32 + hi2 * 16) ^ ((d & 7) << 4)));
        o[dt] = __builtin_amdgcn_mfma_f32_32x32x16_bf16(vf, pf[ks], o[dt], 0, 0, 0);
      }
    }
    if (t + 1 < NTILE) {
      asm volatile("s_waitcnt vmcnt(0)" ::: "memory");
      __syncthreads();
    }
  }
  const float lt = l_acc + __shfl_xor(l_acc, 32);
  const float inv = 1.0f / lt;
  float* orow = Op + (size_t)qrow * ROWS;
#pragma unroll
  for (int dt = 0; dt < 4; ++dt) {
#pragma unroll
    for (int g = 0; g < 4; ++g) {
      float4 v;
      v.x = o[dt][g * 4 + 0] * inv;
      v.y = o[dt][g * 4 + 1] * inv;
      v.z = o[dt][g * 4 + 2] * inv;
      v.w = o[dt][g * 4 + 3] * inv;
      *reinterpret_cast<float4*>(orow + dt * 32 + g * 8 + hi2 * 4) = v;
    }
  }
}

extern "C" void kernel_launch(void* const* d_in, const int* in_sizes, int n_in,
                              void* d_out, int out_size, void* d_ws, size_t ws_size,
                              hipStream_t stream) {
  const float* q = (const float*)d_in[0];
  const float* k = (const float*)d_in[1];
  const float* v = (const float*)d_in[2];
  float* out = (float*)d_out;
  (void)in_sizes; (void)n_in; (void)out_size;
  unsigned short* Kb = (unsigned short*)d_ws;        // ELEMS shorts (16.8 MB)
  unsigned short* Vt = Kb + ELEMS;                   // ELEMS shorts (16.8 MB)
  prepass_kv<<<dim3(NB * NH * NTILE), dim3(256), 0, stream>>>(k, v, Kb, Vt);

  const size_t need_split = (3 * ELEMS + 2 * LCNT) * 4;  // KV + 2xO + 2xl = ~101.2 MB
  if (ws_size >= need_split) {
    float* fw = (float*)d_ws;
    float* Obase = fw + ELEMS;       // KV (2*ELEMS shorts) occupies ELEMS floats
    float* Lbase = Obase + 2 * ELEMS;
    fattn_split<<<dim3(NSPLIT * NQB * NB * NH), dim3(256), 0, stream>>>(
        q, Kb, Vt, Obase, Lbase);
    combine_splits<<<dim3(2048), dim3(256), 0, stream>>>(
        (const float4*)Obase, (const float4*)(Obase + ELEMS), Lbase, Lbase + LCNT,
        (float4*)out, (int)(ELEMS / 4));
  } else {
    fattn_fwd<<<dim3(NQB * NB * NH), dim3(256), 0, stream>>>(q, Kb, Vt, out);
  }
}

// Round 6
// 132.140 us; speedup vs baseline: 2.5598x; 2.5598x over previous
//
#include <hip/hip_runtime.h>
#include <hip/hip_bf16.h>

typedef __attribute__((ext_vector_type(8))) short short8;      // 8 x bf16
typedef __attribute__((ext_vector_type(16))) float f32x16;     // 32x32 MFMA C/D
typedef __attribute__((ext_vector_type(4))) unsigned int uint4v;

#define NB 2
#define NS 2048
#define NH 16
#define ND 128
#define ROWS (NH * ND)       // 2048 floats between consecutive seq positions
#define KVBLK 64
#define QBLK 128             // 4 waves x 32 q-rows
#define NTILE (NS / KVBLK)   // 32
#define NQB (NS / QBLK)      // 16
#define NSPLIT 2
#define TILES_PER_SPLIT (NTILE / NSPLIT)  // 16
#define ELEMS ((size_t)NB * NH * NS * ND)  // 8.39M
#define LCNT ((size_t)NB * NS * NH)        // 65536

__device__ __forceinline__ unsigned short f2bf(float f) {
  union { __hip_bfloat16 b; unsigned short u; } c;
  c.b = __float2bfloat16(f);  // RNE
  return c.u;
}

__device__ __forceinline__ short8 pack8(float4 a, float4 b, float s) {
  short8 r;
  r[0] = (short)f2bf(a.x * s); r[1] = (short)f2bf(a.y * s);
  r[2] = (short)f2bf(a.z * s); r[3] = (short)f2bf(a.w * s);
  r[4] = (short)f2bf(b.x * s); r[5] = (short)f2bf(b.y * s);
  r[6] = (short)f2bf(b.z * s); r[7] = (short)f2bf(b.w * s);
  return r;
}

__device__ __forceinline__ void dma16(const void* g, void* l) {
  __builtin_amdgcn_global_load_lds(
      (const __attribute__((address_space(1))) unsigned int*)g,
      (__attribute__((address_space(3))) unsigned int*)l, 16, 0, 0);
}

__device__ __forceinline__ void pl32swap(unsigned int& a, unsigned int& b) {
  asm("v_permlane32_swap_b32 %0, %1" : "+v"(a), "+v"(b));
}

// ---------------- prepass: K -> bf16 [b,h,s,d]; V -> bf16 transposed [b,h,d,s] ----
__global__ __launch_bounds__(256) void prepass_kv(
    const float* __restrict__ Kg, const float* __restrict__ Vg,
    unsigned short* __restrict__ Kb, unsigned short* __restrict__ Vt) {
  const int blk = blockIdx.x;          // bh*NTILE + t
  const int t = blk & (NTILE - 1);
  const int bh = blk >> 5;
  const int h = bh & (NH - 1);
  const int b = bh >> 4;
  const int tid = threadIdx.x;

  const size_t ibase = (size_t)b * NS * ROWS + (size_t)h * ND + (size_t)t * KVBLK * ROWS;
  const float* Kp = Kg + ibase;
  const float* Vp = Vg + ibase;
  unsigned short* Kbp = Kb + ((size_t)bh * NS + t * KVBLK) * ND;   // [s][d]
  unsigned short* Vtp = Vt + (size_t)bh * ND * NS + t * KVBLK;     // [d][s]

#pragma unroll
  for (int j = 0; j < 4; ++j) {
    const int r = j * 16 + (tid >> 4);
    const int c0 = (tid & 15) * 8;
    float4 a = *reinterpret_cast<const float4*>(Kp + (size_t)r * ROWS + c0);
    float4 c = *reinterpret_cast<const float4*>(Kp + (size_t)r * ROWS + c0 + 4);
    *reinterpret_cast<short8*>(Kbp + r * ND + c0) = pack8(a, c, 1.0f);
  }

  __shared__ float vt[64][129];
#pragma unroll
  for (int j = 0; j < 4; ++j) {
    const int r = j * 16 + (tid >> 4);
    const int c0 = (tid & 15) * 8;
    float4 a = *reinterpret_cast<const float4*>(Vp + (size_t)r * ROWS + c0);
    float4 c = *reinterpret_cast<const float4*>(Vp + (size_t)r * ROWS + c0 + 4);
    vt[r][c0 + 0] = a.x; vt[r][c0 + 1] = a.y; vt[r][c0 + 2] = a.z; vt[r][c0 + 3] = a.w;
    vt[r][c0 + 4] = c.x; vt[r][c0 + 5] = c.y; vt[r][c0 + 6] = c.z; vt[r][c0 + 7] = c.w;
  }
  __syncthreads();
#pragma unroll
  for (int dj = 0; dj < 4; ++dj) {
    const int d = dj * 32 + (tid >> 3);
    const int s0 = (tid & 7) * 8;
    short8 o8;
#pragma unroll
    for (int k = 0; k < 8; ++k) o8[k] = (short)f2bf(vt[s0 + k][d]);
    *reinterpret_cast<short8*>(Vtp + (size_t)d * NS + s0) = o8;
  }
}

// ---------------- split-KV main: 1024 blocks, 16 KV tiles each, partials out ----
// S^T = mfma(A=K, B=Q); O^T = mfma(A=V^T, B=P^T), P^T in-register (permlane32_swap).
// No-max softmax -> splits combine by pure addition: O=(O0+O1)/(l0+l1).
// launch_bounds(256,3): VGPR cap 170 fits the ~165 live set (NO spills — R5's
// (256,4)=128 cap spilled 1.3GB to scratch); 3 waves/SIMD = 12 waves/CU.
__global__ __launch_bounds__(256, 3) void fattn_split(
    const float* __restrict__ Qg, const unsigned short* __restrict__ Kb,
    const unsigned short* __restrict__ Vt, float* __restrict__ Obase,
    float* __restrict__ Lbase) {
  __shared__ __align__(16) char lds[32768];   // single buffer
  char* ksb = lds;
  char* vtb = lds + 16384;
  const int tid = threadIdx.x;
  const int l = tid & 63;
  const int w = tid >> 6;
  const int l31 = l & 31;
  const int hi2 = l >> 5;

  // XCD swizzle (nwg=1024, %8==0), qblk FASTEST in work order: 16 consecutive
  // blocks on one XCD share the same (bh,split) 0.5MB KV-half -> L2-resident.
  const int orig = blockIdx.x;
  const int wg = (orig & 7) * 128 + (orig >> 3);
  const int qblk = wg & (NQB - 1);
  const int split = (wg >> 4) & 1;
  const int bh = wg >> 5;
  const int h = bh & (NH - 1);
  const int b = bh >> 4;

  float* Opart = Obase + (size_t)split * ELEMS;
  float* Lpart = Lbase + (size_t)split * LCNT;

  const float* Qp = Qg + (size_t)b * NS * ROWS + (size_t)h * ND;
  const char* Kbh = (const char*)(Kb + (size_t)bh * NS * ND);   // bf16 [s][d], 256B/row
  const char* Vth = (const char*)(Vt + (size_t)bh * ND * NS);   // bf16 [d][s], 4096B/row

  const float scale = 0.08838834764831845f * 1.4426950408889634f;  // 1/sqrt(D)*log2e

  const int qrow = qblk * QBLK + w * 32 + l31;
  short8 qf[8];
  {
    const float* qr = Qp + (size_t)qrow * ROWS + hi2 * 8;
#pragma unroll
    for (int ks = 0; ks < 8; ++ks) {
      float4 a = *reinterpret_cast<const float4*>(qr + ks * 16);
      float4 c = *reinterpret_cast<const float4*>(qr + ks * 16 + 4);
      qf[ks] = pack8(a, c, scale);
    }
  }

  f32x16 o[4];
#pragma unroll
  for (int dt = 0; dt < 4; ++dt) o[dt] = 0.f;
  float l_acc = 0.f;

  const int t0 = split * TILES_PER_SPLIT;
#pragma unroll 1
  for (int tt = 0; tt < TILES_PER_SPLIT; ++tt) {
    const int t = t0 + tt;
    __syncthreads();  // all waves done reading previous tile

    // K tile DMA: LDS linear, source pre-swizzled (involution (row&7)<<4)
    {
      const char* Kt = Kbh + (size_t)t * KVBLK * 256;
#pragma unroll
      for (int i = 0; i < 4; ++i) {
        const int instr = w * 4 + i;              // 1KB per instr = 4 K-rows
        const int row = instr * 4 + (l >> 4);
        const int x = (l & 15) << 4;
        dma16(Kt + row * 256 + (x ^ ((row & 7) << 4)), ksb + instr * 1024);
      }
    }
    // V^T tile DMA
    {
      const char* Vtt = Vth + (size_t)t * KVBLK * 2;
#pragma unroll
      for (int j = 0; j < 4; ++j) {
        const int instr = w * 4 + j;              // 1KB per instr = 8 V d-rows
        const int d = instr * 8 + (l >> 3);
        const int x = (l & 7) << 4;
        dma16(Vtt + (size_t)d * (NS * 2) + (x ^ ((d & 7) << 4)), vtb + instr * 1024);
      }
    }
    asm volatile("s_waitcnt vmcnt(0)" ::: "memory");
    __syncthreads();

    // Per-mt: S^T(mt) -> exp2 -> l -> pack to pf (keeps peak live regs low)
    short8 pf[4];
#pragma unroll
    for (int mt = 0; mt < 2; ++mt) {
      f32x16 acc = 0.f;
      const int row = mt * 32 + l31;
      __builtin_amdgcn_s_setprio(1);
#pragma unroll
      for (int ks = 0; ks < 8; ++ks) {
        short8 kf = *reinterpret_cast<const short8*>(
            ksb + row * 256 + ((ks * 32 + hi2 * 16) ^ ((row & 7) << 4)));
        acc = __builtin_amdgcn_mfma_f32_32x32x16_bf16(kf, qf[ks], acc, 0, 0, 0);
      }
      __builtin_amdgcn_s_setprio(0);
      f32x16 p;
#pragma unroll
      for (int r = 0; r < 16; ++r) p[r] = exp2f(acc[r]);
      {
        float s = 0.f;
#pragma unroll
        for (int r = 0; r < 16; ++r) s += p[r];
        l_acc += s;
      }
#pragma unroll
      for (int half = 0; half < 2; ++half) {
        unsigned int X[4];
#pragma unroll
        for (int j = 0; j < 4; ++j)
          X[j] = (unsigned int)f2bf(p[half * 8 + 2 * j]) |
                 ((unsigned int)f2bf(p[half * 8 + 2 * j + 1]) << 16);
        pl32swap(X[0], X[2]);
        pl32swap(X[1], X[3]);
        uint4v u = {X[0], X[1], X[2], X[3]};
        pf[mt * 2 + half] = __builtin_bit_cast(short8, u);
      }
    }

    // O^T += V^T P^T : 4 d-tiles x 4 k-steps
    __builtin_amdgcn_s_setprio(1);
#pragma unroll
    for (int dt = 0; dt < 4; ++dt) {
      const int d = dt * 32 + l31;
#pragma unroll
      for (int ks = 0; ks < 4; ++ks) {
        short8 vf = *reinterpret_cast<const short8*>(
            vtb + d * 128 + ((ks * 32 + hi2 * 16) ^ ((d & 7) << 4)));
        o[dt] = __builtin_amdgcn_mfma_f32_32x32x16_bf16(vf, pf[ks], o[dt], 0, 0, 0);
      }
    }
    __builtin_amdgcn_s_setprio(0);
  }

  // epilogue: UNNORMALIZED partial O + l, layout [b,s,h,d] (matches d_out)
  const float lt = l_acc + __shfl_xor(l_acc, 32);
  float* orow = Opart + ((size_t)(b * NS + qrow) * NH + h) * ND;
#pragma unroll
  for (int dt = 0; dt < 4; ++dt) {
#pragma unroll
    for (int g = 0; g < 4; ++g) {
      float4 v;
      v.x = o[dt][g * 4 + 0];
      v.y = o[dt][g * 4 + 1];
      v.z = o[dt][g * 4 + 2];
      v.w = o[dt][g * 4 + 3];
      *reinterpret_cast<float4*>(orow + dt * 32 + g * 8 + hi2 * 4) = v;
    }
  }
  if (hi2 == 0) Lpart[(size_t)(b * NS + qrow) * NH + h] = lt;
}

// ---------------- combine: out = (O0+O1)/(l0+l1), elementwise ----
__global__ __launch_bounds__(256) void combine_splits(
    const float4* __restrict__ O0, const float4* __restrict__ O1,
    const float* __restrict__ L0, const float* __restrict__ L1,
    float4* __restrict__ out, int nf4) {
  int i = blockIdx.x * 256 + threadIdx.x;
  const int stride = gridDim.x * 256;
  for (; i < nf4; i += stride) {
    const int r = i >> 5;  // 32 float4 per 128-d row; r = flat (b,s,h)
    float4 a = O0[i];
    float4 c = O1[i];
    const float inv = 1.0f / (L0[r] + L1[r]);
    float4 v;
    v.x = (a.x + c.x) * inv;
    v.y = (a.y + c.y) * inv;
    v.z = (a.z + c.z) * inv;
    v.w = (a.w + c.w) * inv;
    out[i] = v;
  }
}

// ---------------- fallback (R4 dbuf kernel), used only if ws too small ----------
__global__ __launch_bounds__(256, 2) void fattn_fwd(
    const float* __restrict__ Qg, const unsigned short* __restrict__ Kb,
    const unsigned short* __restrict__ Vt, float* __restrict__ Og) {
  __shared__ __align__(16) char lds[65536];
  const int tid = threadIdx.x;
  const int l = tid & 63;
  const int w = tid >> 6;
  const int l31 = l & 31;
  const int hi2 = l >> 5;
  const int orig = blockIdx.x;
  const int wg = (orig & 7) * 64 + (orig >> 3);
  const int qblk = wg & (NQB - 1);
  const int bh = wg >> 4;
  const int h = bh & (NH - 1);
  const int b = bh >> 4;
  const float* Qp = Qg + (size_t)b * NS * ROWS + (size_t)h * ND;
  float* Op = Og + (size_t)b * NS * ROWS + (size_t)h * ND;
  const char* Kbh = (const char*)(Kb + (size_t)bh * NS * ND);
  const char* Vth = (const char*)(Vt + (size_t)bh * ND * NS);
  const float scale = 0.08838834764831845f * 1.4426950408889634f;
  const int qrow = qblk * QBLK + w * 32 + l31;
  short8 qf[8];
  {
    const float* qr = Qp + (size_t)qrow * ROWS + hi2 * 8;
#pragma unroll
    for (int ks = 0; ks < 8; ++ks) {
      float4 a = *reinterpret_cast<const float4*>(qr + ks * 16);
      float4 c = *reinterpret_cast<const float4*>(qr + ks * 16 + 4);
      qf[ks] = pack8(a, c, scale);
    }
  }
  auto stage = [&](int t, char* kd, char* vd) {
    const char* Kt = Kbh + (size_t)t * KVBLK * 256;
#pragma unroll
    for (int i = 0; i < 4; ++i) {
      const int instr = w * 4 + i;
      const int row = instr * 4 + (l >> 4);
      const int x = (l & 15) << 4;
      dma16(Kt + row * 256 + (x ^ ((row & 7) << 4)), kd + instr * 1024);
    }
    const char* Vtt = Vth + (size_t)t * KVBLK * 2;
#pragma unroll
    for (int j = 0; j < 4; ++j) {
      const int instr = w * 4 + j;
      const int d = instr * 8 + (l >> 3);
      const int x = (l & 7) << 4;
      dma16(Vtt + (size_t)d * (NS * 2) + (x ^ ((d & 7) << 4)), vd + instr * 1024);
    }
  };
  f32x16 o[4];
#pragma unroll
  for (int dt = 0; dt < 4; ++dt) o[dt] = 0.f;
  float l_acc = 0.f;
  stage(0, lds, lds + 16384);
  asm volatile("s_waitcnt vmcnt(0)" ::: "memory");
  __syncthreads();
#pragma unroll 1
  for (int t = 0; t < NTILE; ++t) {
    char* ksb = lds + (t & 1) * 32768;
    char* vtb = ksb + 16384;
    if (t + 1 < NTILE) {
      char* kn = lds + ((t + 1) & 1) * 32768;
      stage(t + 1, kn, kn + 16384);
    }
    short8 pf[4];
#pragma unroll
    for (int mt = 0; mt < 2; ++mt) {
      f32x16 acc = 0.f;
      const int row = mt * 32 + l31;
#pragma unroll
      for (int ks = 0; ks < 8; ++ks) {
        short8 kf = *reinterpret_cast<const short8*>(
            ksb + row * 256 + ((ks * 32 + hi2 * 16) ^ ((row & 7) << 4)));
        acc = __builtin_amdgcn_mfma_f32_32x32x16_bf16(kf, qf[ks], acc, 0, 0, 0);
      }
      f32x16 p;
#pragma unroll
      for (int r = 0; r < 16; ++r) p[r] = exp2f(acc[r]);
      {
        float s = 0.f;
#pragma unroll
        for (int r = 0; r < 16; ++r) s += p[r];
        l_acc += s;
      }
#pragma unroll
      for (int half = 0; half < 2; ++half) {
        unsigned int X[4];
#pragma unroll
        for (int j = 0; j < 4; ++j)
          X[j] = (unsigned int)f2bf(p[half * 8 + 2 * j]) |
                 ((unsigned int)f2bf(p[half * 8 + 2 * j + 1]) << 16);
        pl32swap(X[0], X[2]);
        pl32swap(X[1], X[3]);
        uint4v u = {X[0], X[1], X[2], X[3]};
        pf[mt * 2 + half] = __builtin_bit_cast(short8, u);
      }
    }
#pragma unroll
    for (int dt = 0; dt < 4; ++dt) {
      const int d = dt * 32 + l31;
#pragma unroll
      for (int ks = 0; ks < 4; ++ks) {
        short8 vf = *reinterpret_cast<const short8*>(
            vtb + d * 128 + ((ks * 32 + hi2 * 16) ^ ((d & 7) << 4)));
        o[dt] = __builtin_amdgcn_mfma_f32_32x32x16_bf16(vf, pf[ks], o[dt], 0, 0, 0);
      }
    }
    if (t + 1 < NTILE) {
      asm volatile("s_waitcnt vmcnt(0)" ::: "memory");
      __syncthreads();
    }
  }
  const float lt = l_acc + __shfl_xor(l_acc, 32);
  const float inv = 1.0f / lt;
  float* orow = Op + (size_t)qrow * ROWS;
#pragma unroll
  for (int dt = 0; dt < 4; ++dt) {
#pragma unroll
    for (int g = 0; g < 4; ++g) {
      float4 v;
      v.x = o[dt][g * 4 + 0] * inv;
      v.y = o[dt][g * 4 + 1] * inv;
      v.z = o[dt][g * 4 + 2] * inv;
      v.w = o[dt][g * 4 + 3] * inv;
      *reinterpret_cast<float4*>(orow + dt * 32 + g * 8 + hi2 * 4) = v;
    }
  }
}

extern "C" void kernel_launch(void* const* d_in, const int* in_sizes, int n_in,
                              void* d_out, int out_size, void* d_ws, size_t ws_size,
                              hipStream_t stream) {
  const float* q = (const float*)d_in[0];
  const float* k = (const float*)d_in[1];
  const float* v = (const float*)d_in[2];
  float* out = (float*)d_out;
  (void)in_sizes; (void)n_in; (void)out_size;
  unsigned short* Kb = (unsigned short*)d_ws;        // ELEMS shorts (16.8 MB)
  unsigned short* Vt = Kb + ELEMS;                   // ELEMS shorts (16.8 MB)
  prepass_kv<<<dim3(NB * NH * NTILE), dim3(256), 0, stream>>>(k, v, Kb, Vt);

  const size_t need_split = (3 * ELEMS + 2 * LCNT) * 4;  // KV + 2xO + 2xl = ~101.2 MB
  if (ws_size >= need_split) {
    float* fw = (float*)d_ws;
    float* Obase = fw + ELEMS;       // KV (2*ELEMS shorts) occupies ELEMS floats
    float* Lbase = Obase + 2 * ELEMS;
    fattn_split<<<dim3(NSPLIT * NQB * NB * NH), dim3(256), 0, stream>>>(
        q, Kb, Vt, Obase, Lbase);
    combine_splits<<<dim3(2048), dim3(256), 0, stream>>>(
        (const float4*)Obase, (const float4*)(Obase + ELEMS), Lbase, Lbase + LCNT,
        (float4*)out, (int)(ELEMS / 4));
  } else {
    fattn_fwd<<<dim3(NQB * NB * NH), dim3(256), 0, stream>>>(q, Kb, Vt, out);
  }
}